// Round 11
// baseline (333.258 us; speedup 1.0000x reference)
//
#include <hip/hip_runtime.h>

// VectorQuantizer: z (8,64,8192) f32, codebook (1024,64) f32
// Outputs (concatenated f32): z_q_st [4194304], vq_loss [1], codes [65536]
//
// codes must match numpy fp32 argmin BIT-EXACTLY -> replicate numpy op order:
//   zsq/wsq: pairwise_sum n=64 (8 serial column accumulators, rounded squares)
//   dot:     single serial FMA chain over k ascending (BLAS sgemm order)
//   dist:    fl(fl(zsq - fl(2*dot)) + wsq), argmin = first occurrence of min.
//
// Evidence ledger:
//   R6-R9: row-per-thread, w via s_load: 190us invariant. R11: w per-lane
//     VMEM: 500us (64x L1 amplification). R12: transpose: 209us. R13: batch
//     4 rows: 175us. R14: sw-pipeline: 1667us SPILL (revert). R15: fused
//     single kernel: 184.7us kernel / 223.8 total. VALUBusy 54.9%.
//   CONFIRMED MODEL (R13/R15): core is LDS-throughput-bound. Per CU per
//     iter-round: 8 waves x ~96 LDS instr ~= 6100cy vs 2048cy VALU/SIMD --
//     3x oversubscribed because all 8 waves broadcast-read IDENTICAL z.
//   R15 bank conflicts 477k: epilogue scalar reads from 16B-strided float4
//     (8 lanes/bank). Fix: read full float4 (contiguous b128 = free).
// R16 (this round): 4 waves x 4 CODES/LANE (256 codes/wave, w = 64 float4
//   ~ 256 regs). Same FMA work; z-broadcast redundancy 8x -> 4x; per CU
//   iter-round LDS ~2500cy vs VALU 2048cy -> near-balanced. block=256,
//   __launch_bounds__(256,1) -> up to 512 unified regs/wave (1 wave/SIMD);
//   CDNA2+ VALU reads AGPRs directly (R6 lesson) so >256 regs is fine.
//   16 indep FMA chains saturate VALU from 1 wave. Reduction: per-row
//   4-class fmin + 6 interleaved shfl + 4 class-ordered ballots (class
//   order = code order -> first-min preserved). NO duplicated FMA blocks
//   (R14 lesson).
//   Predict: kernel 184.7 -> 95-135us; total -> 130-170us; VGPR ~250+;
//   conflicts 477k -> ~20k; FETCH ~9.3MB unchanged.
//   Falsifier A: FETCH GB-scale = spill -> revert to 2 codes/lane.
//   Falsifier B: dur flat w/ VGPR~108 -> compiler refused wide alloc.

#define T_DIM 8192
#define D_DIM 64
#define C_DIM 1024
#define B_DIM 8
#define NROWS (B_DIM * T_DIM)           // 65536 vectors
#define NELEM (B_DIM * D_DIM * T_DIM)   // 4194304 elements
#define NBLKS (NROWS / 256)             // 256 fused blocks

#define R64(M) M(0) M(1) M(2) M(3) M(4) M(5) M(6) M(7) \
  M(8) M(9) M(10) M(11) M(12) M(13) M(14) M(15) \
  M(16) M(17) M(18) M(19) M(20) M(21) M(22) M(23) \
  M(24) M(25) M(26) M(27) M(28) M(29) M(30) M(31) \
  M(32) M(33) M(34) M(35) M(36) M(37) M(38) M(39) \
  M(40) M(41) M(42) M(43) M(44) M(45) M(46) M(47) \
  M(48) M(49) M(50) M(51) M(52) M(53) M(54) M(55) \
  M(56) M(57) M(58) M(59) M(60) M(61) M(62) M(63)

#define SQ_(x) __fmul_rn(x, x)
#define AD_(a, b) __fadd_rn(a, b)

// numpy pairwise_sum of 64 pre-rounded squares of scalars p0..p63 -> dst.
#define PAIRWISE64(p, dst) \
  float pr0 = SQ_(p##0);  pr0 = AD_(pr0, SQ_(p##8));  pr0 = AD_(pr0, SQ_(p##16)); pr0 = AD_(pr0, SQ_(p##24)); pr0 = AD_(pr0, SQ_(p##32)); pr0 = AD_(pr0, SQ_(p##40)); pr0 = AD_(pr0, SQ_(p##48)); pr0 = AD_(pr0, SQ_(p##56)); \
  float pr1 = SQ_(p##1);  pr1 = AD_(pr1, SQ_(p##9));  pr1 = AD_(pr1, SQ_(p##17)); pr1 = AD_(pr1, SQ_(p##25)); pr1 = AD_(pr1, SQ_(p##33)); pr1 = AD_(pr1, SQ_(p##41)); pr1 = AD_(pr1, SQ_(p##49)); pr1 = AD_(pr1, SQ_(p##57)); \
  float pr2 = SQ_(p##2);  pr2 = AD_(pr2, SQ_(p##10)); pr2 = AD_(pr2, SQ_(p##18)); pr2 = AD_(pr2, SQ_(p##26)); pr2 = AD_(pr2, SQ_(p##34)); pr2 = AD_(pr2, SQ_(p##42)); pr2 = AD_(pr2, SQ_(p##50)); pr2 = AD_(pr2, SQ_(p##58)); \
  float pr3 = SQ_(p##3);  pr3 = AD_(pr3, SQ_(p##11)); pr3 = AD_(pr3, SQ_(p##19)); pr3 = AD_(pr3, SQ_(p##27)); pr3 = AD_(pr3, SQ_(p##35)); pr3 = AD_(pr3, SQ_(p##43)); pr3 = AD_(pr3, SQ_(p##51)); pr3 = AD_(pr3, SQ_(p##59)); \
  float pr4 = SQ_(p##4);  pr4 = AD_(pr4, SQ_(p##12)); pr4 = AD_(pr4, SQ_(p##20)); pr4 = AD_(pr4, SQ_(p##28)); pr4 = AD_(pr4, SQ_(p##36)); pr4 = AD_(pr4, SQ_(p##44)); pr4 = AD_(pr4, SQ_(p##52)); pr4 = AD_(pr4, SQ_(p##60)); \
  float pr5 = SQ_(p##5);  pr5 = AD_(pr5, SQ_(p##13)); pr5 = AD_(pr5, SQ_(p##21)); pr5 = AD_(pr5, SQ_(p##29)); pr5 = AD_(pr5, SQ_(p##37)); pr5 = AD_(pr5, SQ_(p##45)); pr5 = AD_(pr5, SQ_(p##53)); pr5 = AD_(pr5, SQ_(p##61)); \
  float pr6 = SQ_(p##6);  pr6 = AD_(pr6, SQ_(p##14)); pr6 = AD_(pr6, SQ_(p##22)); pr6 = AD_(pr6, SQ_(p##30)); pr6 = AD_(pr6, SQ_(p##38)); pr6 = AD_(pr6, SQ_(p##46)); pr6 = AD_(pr6, SQ_(p##54)); pr6 = AD_(pr6, SQ_(p##62)); \
  float pr7 = SQ_(p##7);  pr7 = AD_(pr7, SQ_(p##15)); pr7 = AD_(pr7, SQ_(p##23)); pr7 = AD_(pr7, SQ_(p##31)); pr7 = AD_(pr7, SQ_(p##39)); pr7 = AD_(pr7, SQ_(p##47)); pr7 = AD_(pr7, SQ_(p##55)); pr7 = AD_(pr7, SQ_(p##63)); \
  float dst = AD_(AD_(AD_(pr0, pr1), AD_(pr2, pr3)), AD_(AD_(pr4, pr5), AD_(pr6, pr7)));

// Same pairwise order, sourced from a float4[16] register array.
#define WSQ_OF(arr, dst) float dst; { \
  float c0 = SQ_(arr[0].x); c0=AD_(c0,SQ_(arr[2].x)); c0=AD_(c0,SQ_(arr[4].x)); c0=AD_(c0,SQ_(arr[6].x)); c0=AD_(c0,SQ_(arr[8].x)); c0=AD_(c0,SQ_(arr[10].x)); c0=AD_(c0,SQ_(arr[12].x)); c0=AD_(c0,SQ_(arr[14].x)); \
  float c1 = SQ_(arr[0].y); c1=AD_(c1,SQ_(arr[2].y)); c1=AD_(c1,SQ_(arr[4].y)); c1=AD_(c1,SQ_(arr[6].y)); c1=AD_(c1,SQ_(arr[8].y)); c1=AD_(c1,SQ_(arr[10].y)); c1=AD_(c1,SQ_(arr[12].y)); c1=AD_(c1,SQ_(arr[14].y)); \
  float c2 = SQ_(arr[0].z); c2=AD_(c2,SQ_(arr[2].z)); c2=AD_(c2,SQ_(arr[4].z)); c2=AD_(c2,SQ_(arr[6].z)); c2=AD_(c2,SQ_(arr[8].z)); c2=AD_(c2,SQ_(arr[10].z)); c2=AD_(c2,SQ_(arr[12].z)); c2=AD_(c2,SQ_(arr[14].z)); \
  float c3 = SQ_(arr[0].w); c3=AD_(c3,SQ_(arr[2].w)); c3=AD_(c3,SQ_(arr[4].w)); c3=AD_(c3,SQ_(arr[6].w)); c3=AD_(c3,SQ_(arr[8].w)); c3=AD_(c3,SQ_(arr[10].w)); c3=AD_(c3,SQ_(arr[12].w)); c3=AD_(c3,SQ_(arr[14].w)); \
  float c4 = SQ_(arr[1].x); c4=AD_(c4,SQ_(arr[3].x)); c4=AD_(c4,SQ_(arr[5].x)); c4=AD_(c4,SQ_(arr[7].x)); c4=AD_(c4,SQ_(arr[9].x)); c4=AD_(c4,SQ_(arr[11].x)); c4=AD_(c4,SQ_(arr[13].x)); c4=AD_(c4,SQ_(arr[15].x)); \
  float c5 = SQ_(arr[1].y); c5=AD_(c5,SQ_(arr[3].y)); c5=AD_(c5,SQ_(arr[5].y)); c5=AD_(c5,SQ_(arr[7].y)); c5=AD_(c5,SQ_(arr[9].y)); c5=AD_(c5,SQ_(arr[11].y)); c5=AD_(c5,SQ_(arr[13].y)); c5=AD_(c5,SQ_(arr[15].y)); \
  float c6 = SQ_(arr[1].z); c6=AD_(c6,SQ_(arr[3].z)); c6=AD_(c6,SQ_(arr[5].z)); c6=AD_(c6,SQ_(arr[7].z)); c6=AD_(c6,SQ_(arr[9].z)); c6=AD_(c6,SQ_(arr[11].z)); c6=AD_(c6,SQ_(arr[13].z)); c6=AD_(c6,SQ_(arr[15].z)); \
  float c7 = SQ_(arr[1].w); c7=AD_(c7,SQ_(arr[3].w)); c7=AD_(c7,SQ_(arr[5].w)); c7=AD_(c7,SQ_(arr[7].w)); c7=AD_(c7,SQ_(arr[9].w)); c7=AD_(c7,SQ_(arr[11].w)); c7=AD_(c7,SQ_(arr[13].w)); c7=AD_(c7,SQ_(arr[15].w)); \
  dst = AD_(AD_(AD_(c0, c1), AD_(c2, c3)), AD_(AD_(c4, c5), AD_(c6, c7))); }

// One FMA chain-step: 4 serial FMAs (k ascending within the float4).
#define FM4(acc, zc, W) \
    acc = fmaf(zc.x, W.x, acc); acc = fmaf(zc.y, W.y, acc); \
    acc = fmaf(zc.z, W.z, acc); acc = fmaf(zc.w, W.w, acc);

// Fused kernel: 256 threads = 4 waves; each wave owns 256 codes (4/lane:
// cbase+lane, +64, +128, +192; w in ~256 regs, VALU reads AGPRs directly).
// 256-row z tile in LDS (broadcast reads, 4x redundancy instead of 8x).
// 4 rows/iter: 16 indep FMA chains; per-row 4-class fmin + 6 interleaved
// shfl levels + class-ordered ballots. Fused epilogue + loss partial.
__global__ __launch_bounds__(256, 1)
void vq_fused_kernel(const float* __restrict__ z,
                     const float* __restrict__ cb,
                     float* __restrict__ out,
                     float* __restrict__ codes,
                     double* __restrict__ partials) {
    const int tid  = threadIdx.x;                     // 0..255
    const int wid  = tid >> 6;                        // 0..3
    const int lane = tid & 63;
    const int row0 = blockIdx.x * 256;                // tile base (same b)
    const int b    = row0 >> 13;                      // 8192 % 256 == 0
    const int t0   = row0 & (T_DIM - 1);

    __shared__ float4 zl[16][256];                    // 64 KiB [kchunk][row]
    __shared__ float  zsql[256];                      // 1 KiB
    __shared__ float2 res[4][256];                    // 8 KiB  [wave][row]
    __shared__ int    codesl[256];                    // 1 KiB

    // --- stage z tile: thread tid handles row row0+tid (coalesced) ---
    {
        const float* zp = z + (size_t)b * (D_DIM * T_DIM) + (t0 + tid);
#define LOADZ(k) float z##k = zp[(size_t)k * T_DIM];
        R64(LOADZ)
#undef LOADZ
        PAIRWISE64(z, zsq)
        zsql[tid] = zsq;
        zl[ 0][tid] = make_float4(z0,  z1,  z2,  z3);
        zl[ 1][tid] = make_float4(z4,  z5,  z6,  z7);
        zl[ 2][tid] = make_float4(z8,  z9,  z10, z11);
        zl[ 3][tid] = make_float4(z12, z13, z14, z15);
        zl[ 4][tid] = make_float4(z16, z17, z18, z19);
        zl[ 5][tid] = make_float4(z20, z21, z22, z23);
        zl[ 6][tid] = make_float4(z24, z25, z26, z27);
        zl[ 7][tid] = make_float4(z28, z29, z30, z31);
        zl[ 8][tid] = make_float4(z32, z33, z34, z35);
        zl[ 9][tid] = make_float4(z36, z37, z38, z39);
        zl[10][tid] = make_float4(z40, z41, z42, z43);
        zl[11][tid] = make_float4(z44, z45, z46, z47);
        zl[12][tid] = make_float4(z48, z49, z50, z51);
        zl[13][tid] = make_float4(z52, z53, z54, z55);
        zl[14][tid] = make_float4(z56, z57, z58, z59);
        zl[15][tid] = make_float4(z60, z61, z62, z63);
    }

    // --- my four codes' w into registers (one-time; 64 x float4) ---
    const int cbase = wid * 256;                      // wave's code base
    float4 wa[16], wb[16], wc[16], wd[16];
    {
        const float4* wpa = (const float4*)(cb + ((size_t)(cbase + lane)       << 6));
        const float4* wpb = (const float4*)(cb + ((size_t)(cbase + lane + 64)  << 6));
        const float4* wpc = (const float4*)(cb + ((size_t)(cbase + lane + 128) << 6));
        const float4* wpd = (const float4*)(cb + ((size_t)(cbase + lane + 192) << 6));
#pragma unroll
        for (int kk = 0; kk < 16; ++kk) {
            wa[kk] = wpa[kk]; wb[kk] = wpb[kk];
            wc[kk] = wpc[kk]; wd[kk] = wpd[kk];
        }
    }
    WSQ_OF(wa, wsqA)
    WSQ_OF(wb, wsqB)
    WSQ_OF(wc, wsqC)
    WSQ_OF(wd, wsqD)
    __syncthreads();

    // --- row loop: 4 rows/iter, 16 indep FMA chains, per-row argmin ---
#pragma unroll 1
    for (int r = 0; r < 256; r += 4) {
        float aA0 = 0.f, aA1 = 0.f, aA2 = 0.f, aA3 = 0.f;
        float aB0 = 0.f, aB1 = 0.f, aB2 = 0.f, aB3 = 0.f;
        float aC0 = 0.f, aC1 = 0.f, aC2 = 0.f, aC3 = 0.f;
        float aD0 = 0.f, aD1 = 0.f, aD2 = 0.f, aD3 = 0.f;
#pragma unroll
        for (int kk = 0; kk < 16; ++kk) {
            const float4 zc0 = zl[kk][r + 0];   // broadcast reads
            const float4 zc1 = zl[kk][r + 1];
            const float4 zc2 = zl[kk][r + 2];
            const float4 zc3 = zl[kk][r + 3];
            const float4 WA = wa[kk];
            const float4 WB = wb[kk];
            const float4 WC = wc[kk];
            const float4 WD = wd[kk];
            FM4(aA0, zc0, WA) FM4(aA1, zc1, WA) FM4(aA2, zc2, WA) FM4(aA3, zc3, WA)
            FM4(aB0, zc0, WB) FM4(aB1, zc1, WB) FM4(aB2, zc2, WB) FM4(aB3, zc3, WB)
            FM4(aC0, zc0, WC) FM4(aC1, zc1, WC) FM4(aC2, zc2, WC) FM4(aC3, zc3, WC)
            FM4(aD0, zc0, WD) FM4(aD1, zc1, WD) FM4(aD2, zc2, WD) FM4(aD3, zc3, WD)
        }
        const float zr0 = zsql[r + 0];
        const float zr1 = zsql[r + 1];
        const float zr2 = zsql[r + 2];
        const float zr3 = zsql[r + 3];
        // d = (zsq - 2*dot) + wsq, each op individually rounded
        const float dA0 = __fadd_rn(__fsub_rn(zr0, __fmul_rn(2.0f, aA0)), wsqA);
        const float dB0 = __fadd_rn(__fsub_rn(zr0, __fmul_rn(2.0f, aB0)), wsqB);
        const float dC0 = __fadd_rn(__fsub_rn(zr0, __fmul_rn(2.0f, aC0)), wsqC);
        const float dD0 = __fadd_rn(__fsub_rn(zr0, __fmul_rn(2.0f, aD0)), wsqD);
        const float dA1 = __fadd_rn(__fsub_rn(zr1, __fmul_rn(2.0f, aA1)), wsqA);
        const float dB1 = __fadd_rn(__fsub_rn(zr1, __fmul_rn(2.0f, aB1)), wsqB);
        const float dC1 = __fadd_rn(__fsub_rn(zr1, __fmul_rn(2.0f, aC1)), wsqC);
        const float dD1 = __fadd_rn(__fsub_rn(zr1, __fmul_rn(2.0f, aD1)), wsqD);
        const float dA2 = __fadd_rn(__fsub_rn(zr2, __fmul_rn(2.0f, aA2)), wsqA);
        const float dB2 = __fadd_rn(__fsub_rn(zr2, __fmul_rn(2.0f, aB2)), wsqB);
        const float dC2 = __fadd_rn(__fsub_rn(zr2, __fmul_rn(2.0f, aC2)), wsqC);
        const float dD2 = __fadd_rn(__fsub_rn(zr2, __fmul_rn(2.0f, aD2)), wsqD);
        const float dA3 = __fadd_rn(__fsub_rn(zr3, __fmul_rn(2.0f, aA3)), wsqA);
        const float dB3 = __fadd_rn(__fsub_rn(zr3, __fmul_rn(2.0f, aB3)), wsqB);
        const float dC3 = __fadd_rn(__fsub_rn(zr3, __fmul_rn(2.0f, aC3)), wsqC);
        const float dD3 = __fadd_rn(__fsub_rn(zr3, __fmul_rn(2.0f, aD3)), wsqD);
        // per-lane 4-class min (value only; class resolved by ballots below)
        float m0 = fminf(fminf(dA0, dB0), fminf(dC0, dD0));
        float m1 = fminf(fminf(dA1, dB1), fminf(dC1, dD1));
        float m2 = fminf(fminf(dA2, dB2), fminf(dC2, dD2));
        float m3 = fminf(fminf(dA3, dB3), fminf(dC3, dD3));
        // 4 independent wave-min chains, interleaved -> pipelined bpermutes
#pragma unroll
        for (int off = 32; off > 0; off >>= 1) {
            m0 = fminf(m0, __shfl_xor(m0, off, 64));
            m1 = fminf(m1, __shfl_xor(m1, off, 64));
            m2 = fminf(m2, __shfl_xor(m2, off, 64));
            m3 = fminf(m3, __shfl_xor(m3, off, 64));
        }
        // first-min: class A codes < B < C < D; within a class lane order
        // == code order -> check classes ascending, lowest set lane wins.
#define ARG4(mj, dAj, dBj, dCj, dDj, outIdx) { \
        const unsigned long long kA = __ballot(dAj == mj); \
        const unsigned long long kB = __ballot(dBj == mj); \
        const unsigned long long kC = __ballot(dCj == mj); \
        const unsigned long long kD = __ballot(dDj == mj); \
        int code; \
        if (kA)      code = cbase +       (__ffsll((long long)kA) - 1); \
        else if (kB) code = cbase + 64  + (__ffsll((long long)kB) - 1); \
        else if (kC) code = cbase + 128 + (__ffsll((long long)kC) - 1); \
        else         code = cbase + 192 + (__ffsll((long long)kD) - 1); \
        if (lane == 0) res[wid][outIdx] = make_float2(mj, (float)code); }
        ARG4(m0, dA0, dB0, dC0, dD0, r + 0)
        ARG4(m1, dA1, dB1, dC1, dD1, r + 1)
        ARG4(m2, dA2, dB2, dC2, dD2, r + 2)
        ARG4(m3, dA3, dB3, dC3, dD3, r + 3)
#undef ARG4
    }
    __syncthreads();

    // --- combine 4 waves (ascending wid == ascending code blocks) ---
    {
        float2 best = res[0][tid];
#pragma unroll
        for (int w = 1; w < 4; ++w) {
            const float2 p = res[w][tid];
            if (p.x < best.x) best = p;   // strict < keeps lower codes
        }
        codes[row0 + tid] = best.y;
        codesl[tid] = (int)best.y;
    }
    __syncthreads();

    // --- fused epilogue: thread tid owns row tl=tid; 16 float4 chunks ---
    // zl read contiguous b128 (conflict-free); cb read as float4 gather;
    // stores per d-plane coalesced. out = fl(z + fl(w - z)).
    const int tl = tid;
    const int code = codesl[tl];
    double lsum = 0.0;
    float* outb = out + (size_t)b * (D_DIM * T_DIM) + t0 + tl;
#pragma unroll 1
    for (int it = 0; it < 16; ++it) {
        const float4 z4 = zl[it][tl];
        const float4 w4 = *(const float4*)(cb + ((size_t)code << 6) + (it << 2));
        const float df0 = __fsub_rn(w4.x, z4.x);
        const float df1 = __fsub_rn(w4.y, z4.y);
        const float df2 = __fsub_rn(w4.z, z4.z);
        const float df3 = __fsub_rn(w4.w, z4.w);
        outb[(size_t)((it << 2) + 0) * T_DIM] = __fadd_rn(z4.x, df0);
        outb[(size_t)((it << 2) + 1) * T_DIM] = __fadd_rn(z4.y, df1);
        outb[(size_t)((it << 2) + 2) * T_DIM] = __fadd_rn(z4.z, df2);
        outb[(size_t)((it << 2) + 3) * T_DIM] = __fadd_rn(z4.w, df3);
        lsum += (double)df0 * df0 + (double)df1 * df1
              + (double)df2 * df2 + (double)df3 * df3;
    }
    // wave reduce (double) then block reduce via LDS
#pragma unroll
    for (int o2 = 32; o2 > 0; o2 >>= 1) lsum += __shfl_down(lsum, o2, 64);
    __shared__ double redd[4];
    if (lane == 0) redd[wid] = lsum;
    __syncthreads();
    if (tid == 0)
        partials[blockIdx.x] = (redd[0] + redd[1]) + (redd[2] + redd[3]);
}

__global__ void vq_loss_kernel(const double* __restrict__ partials,
                               float* __restrict__ out_loss) {
    double s = 0.0;
    for (int i = threadIdx.x; i < NBLKS; i += 256) s += partials[i];
#pragma unroll
    for (int o = 32; o > 0; o >>= 1) s += __shfl_down(s, o, 64);
    __shared__ double red[4];
    if ((threadIdx.x & 63) == 0) red[threadIdx.x >> 6] = s;
    __syncthreads();
    if (threadIdx.x == 0) {
        double tot = (red[0] + red[1]) + (red[2] + red[3]);
        // vq_loss = codebook_loss + 0.25*commitment_loss = 1.25*mean(diff^2)
        out_loss[0] = (float)(1.25 * tot / (double)NELEM);
    }
}

extern "C" void kernel_launch(void* const* d_in, const int* in_sizes, int n_in,
                              void* d_out, int out_size, void* d_ws, size_t ws_size,
                              hipStream_t stream) {
    const float* z  = (const float*)d_in[0];   // 4194304
    const float* cb = (const float*)d_in[1];   // 65536

    float* out      = (float*)d_out;
    float* out_loss = out + NELEM;             // index 4194304
    float* codes    = out + NELEM + 1;         // 65536 floats

    double* partials = (double*)d_ws;          // 2 KiB (256 doubles)

    vq_fused_kernel<<<NBLKS, 256, 0, stream>>>(z, cb, out, codes, partials);
    vq_loss_kernel<<<1, 256, 0, stream>>>(partials, out_loss);
}

// Round 12
// 302.664 us; speedup vs baseline: 1.1011x; 1.1011x over previous
//
#include <hip/hip_runtime.h>

// VectorQuantizer: z (8,64,8192) f32, codebook (1024,64) f32
// Outputs (concatenated f32): z_q_st [4194304], vq_loss [1], codes [65536]
//
// codes must match numpy fp32 argmin BIT-EXACTLY -> replicate numpy op order:
//   zsq/wsq: pairwise_sum n=64 (8 serial column accumulators, rounded squares)
//   dot:     single serial FMA chain over k ascending (BLAS sgemm order)
//   dist:    fl(fl(zsq - fl(2*dot)) + wsq), argmin = first occurrence of min.
//
// Evidence ledger:
//   R6-R9: row-per-thread, w via s_load: 190us invariant. R11: w per-lane
//     VMEM: 500us. R12: transpose: 209us. R13: batch 4 rows: 175us.
//   R14: sw-pipeline: 1667us SPILL (revert). R15: fused 8w x 2codes/lane,
//     256-row tile: 184.7us kernel / 223.8 total, VALUBusy 55%, 2 w/SIMD.
//   R16: 4w x 4codes/lane, launch_bounds(256,1): 288us, VALUBusy 29%,
//     1 wave/SIMD -- latency fully exposed. REFUTES pure LDS-throughput
//     model: R15 arithmetic rebalanced = LDS ~2048cy/CU vs VALU 2048cy/SIMD
//     per iter-round (balanced), yet wall ~6900cy -> the core is
//     LATENCY/DEPENDENCY-bound at 2 waves/SIMD. Lever = TLP.
// R17 (this round): R15 core verbatim, tile HALVED to 128 rows ->
//   LDS 82->42KB -> 2 blocks/CU -> 16 waves/CU = 4 waves/SIMD (VGPR 108
//   <= 128 cap). Per-CU LDS traffic per row IDENTICAL -> clean TLP-only
//   experiment. Staging spread over all 512 threads; zsq recomputed from
//   LDS bits in exact PAIRWISE64 order (same values -> same bits).
//   Epilogue = conflict-free b128 reads.
//   Predict: kernel 184.7 -> 120-145us; total -> 160-185; Occ ~45-50%.
//   Falsifier A: FETCH GB-scale = spill at 128-cap -> relax bound.
//   Falsifier B: flat ~185 -> LDS-throughput-bound -> cut redundancy next.

#define T_DIM 8192
#define D_DIM 64
#define C_DIM 1024
#define B_DIM 8
#define NROWS (B_DIM * T_DIM)           // 65536 vectors
#define NELEM (B_DIM * D_DIM * T_DIM)   // 4194304 elements
#define TROWS 128                       // rows per block tile
#define NBLKS (NROWS / TROWS)           // 512 fused blocks

#define SQ_(x) __fmul_rn(x, x)
#define AD_(a, b) __fadd_rn(a, b)

// numpy pairwise_sum of 64 pre-rounded squares of scalars p0..p63 -> dst.
#define PAIRWISE64(p, dst) \
  float pr0 = SQ_(p##0);  pr0 = AD_(pr0, SQ_(p##8));  pr0 = AD_(pr0, SQ_(p##16)); pr0 = AD_(pr0, SQ_(p##24)); pr0 = AD_(pr0, SQ_(p##32)); pr0 = AD_(pr0, SQ_(p##40)); pr0 = AD_(pr0, SQ_(p##48)); pr0 = AD_(pr0, SQ_(p##56)); \
  float pr1 = SQ_(p##1);  pr1 = AD_(pr1, SQ_(p##9));  pr1 = AD_(pr1, SQ_(p##17)); pr1 = AD_(pr1, SQ_(p##25)); pr1 = AD_(pr1, SQ_(p##33)); pr1 = AD_(pr1, SQ_(p##41)); pr1 = AD_(pr1, SQ_(p##49)); pr1 = AD_(pr1, SQ_(p##57)); \
  float pr2 = SQ_(p##2);  pr2 = AD_(pr2, SQ_(p##10)); pr2 = AD_(pr2, SQ_(p##18)); pr2 = AD_(pr2, SQ_(p##26)); pr2 = AD_(pr2, SQ_(p##34)); pr2 = AD_(pr2, SQ_(p##42)); pr2 = AD_(pr2, SQ_(p##50)); pr2 = AD_(pr2, SQ_(p##58)); \
  float pr3 = SQ_(p##3);  pr3 = AD_(pr3, SQ_(p##11)); pr3 = AD_(pr3, SQ_(p##19)); pr3 = AD_(pr3, SQ_(p##27)); pr3 = AD_(pr3, SQ_(p##35)); pr3 = AD_(pr3, SQ_(p##43)); pr3 = AD_(pr3, SQ_(p##51)); pr3 = AD_(pr3, SQ_(p##59)); \
  float pr4 = SQ_(p##4);  pr4 = AD_(pr4, SQ_(p##12)); pr4 = AD_(pr4, SQ_(p##20)); pr4 = AD_(pr4, SQ_(p##28)); pr4 = AD_(pr4, SQ_(p##36)); pr4 = AD_(pr4, SQ_(p##44)); pr4 = AD_(pr4, SQ_(p##52)); pr4 = AD_(pr4, SQ_(p##60)); \
  float pr5 = SQ_(p##5);  pr5 = AD_(pr5, SQ_(p##13)); pr5 = AD_(pr5, SQ_(p##21)); pr5 = AD_(pr5, SQ_(p##29)); pr5 = AD_(pr5, SQ_(p##37)); pr5 = AD_(pr5, SQ_(p##45)); pr5 = AD_(pr5, SQ_(p##53)); pr5 = AD_(pr5, SQ_(p##61)); \
  float pr6 = SQ_(p##6);  pr6 = AD_(pr6, SQ_(p##14)); pr6 = AD_(pr6, SQ_(p##22)); pr6 = AD_(pr6, SQ_(p##30)); pr6 = AD_(pr6, SQ_(p##38)); pr6 = AD_(pr6, SQ_(p##46)); pr6 = AD_(pr6, SQ_(p##54)); pr6 = AD_(pr6, SQ_(p##62)); \
  float pr7 = SQ_(p##7);  pr7 = AD_(pr7, SQ_(p##15)); pr7 = AD_(pr7, SQ_(p##23)); pr7 = AD_(pr7, SQ_(p##31)); pr7 = AD_(pr7, SQ_(p##39)); pr7 = AD_(pr7, SQ_(p##47)); pr7 = AD_(pr7, SQ_(p##55)); pr7 = AD_(pr7, SQ_(p##63)); \
  float dst = AD_(AD_(AD_(pr0, pr1), AD_(pr2, pr3)), AD_(AD_(pr4, pr5), AD_(pr6, pr7)));

// Same pairwise order, sourced from a float4[16] register array.
#define WSQ_OF(arr, dst) float dst; { \
  float c0 = SQ_(arr[0].x); c0=AD_(c0,SQ_(arr[2].x)); c0=AD_(c0,SQ_(arr[4].x)); c0=AD_(c0,SQ_(arr[6].x)); c0=AD_(c0,SQ_(arr[8].x)); c0=AD_(c0,SQ_(arr[10].x)); c0=AD_(c0,SQ_(arr[12].x)); c0=AD_(c0,SQ_(arr[14].x)); \
  float c1 = SQ_(arr[0].y); c1=AD_(c1,SQ_(arr[2].y)); c1=AD_(c1,SQ_(arr[4].y)); c1=AD_(c1,SQ_(arr[6].y)); c1=AD_(c1,SQ_(arr[8].y)); c1=AD_(c1,SQ_(arr[10].y)); c1=AD_(c1,SQ_(arr[12].y)); c1=AD_(c1,SQ_(arr[14].y)); \
  float c2 = SQ_(arr[0].z); c2=AD_(c2,SQ_(arr[2].z)); c2=AD_(c2,SQ_(arr[4].z)); c2=AD_(c2,SQ_(arr[6].z)); c2=AD_(c2,SQ_(arr[8].z)); c2=AD_(c2,SQ_(arr[10].z)); c2=AD_(c2,SQ_(arr[12].z)); c2=AD_(c2,SQ_(arr[14].z)); \
  float c3 = SQ_(arr[0].w); c3=AD_(c3,SQ_(arr[2].w)); c3=AD_(c3,SQ_(arr[4].w)); c3=AD_(c3,SQ_(arr[6].w)); c3=AD_(c3,SQ_(arr[8].w)); c3=AD_(c3,SQ_(arr[10].w)); c3=AD_(c3,SQ_(arr[12].w)); c3=AD_(c3,SQ_(arr[14].w)); \
  float c4 = SQ_(arr[1].x); c4=AD_(c4,SQ_(arr[3].x)); c4=AD_(c4,SQ_(arr[5].x)); c4=AD_(c4,SQ_(arr[7].x)); c4=AD_(c4,SQ_(arr[9].x)); c4=AD_(c4,SQ_(arr[11].x)); c4=AD_(c4,SQ_(arr[13].x)); c4=AD_(c4,SQ_(arr[15].x)); \
  float c5 = SQ_(arr[1].y); c5=AD_(c5,SQ_(arr[3].y)); c5=AD_(c5,SQ_(arr[5].y)); c5=AD_(c5,SQ_(arr[7].y)); c5=AD_(c5,SQ_(arr[9].y)); c5=AD_(c5,SQ_(arr[11].y)); c5=AD_(c5,SQ_(arr[13].y)); c5=AD_(c5,SQ_(arr[15].y)); \
  float c6 = SQ_(arr[1].z); c6=AD_(c6,SQ_(arr[3].z)); c6=AD_(c6,SQ_(arr[5].z)); c6=AD_(c6,SQ_(arr[7].z)); c6=AD_(c6,SQ_(arr[9].z)); c6=AD_(c6,SQ_(arr[11].z)); c6=AD_(c6,SQ_(arr[13].z)); c6=AD_(c6,SQ_(arr[15].z)); \
  float c7 = SQ_(arr[1].w); c7=AD_(c7,SQ_(arr[3].w)); c7=AD_(c7,SQ_(arr[5].w)); c7=AD_(c7,SQ_(arr[7].w)); c7=AD_(c7,SQ_(arr[9].w)); c7=AD_(c7,SQ_(arr[11].w)); c7=AD_(c7,SQ_(arr[13].w)); c7=AD_(c7,SQ_(arr[15].w)); \
  dst = AD_(AD_(AD_(c0, c1), AD_(c2, c3)), AD_(AD_(c4, c5), AD_(c6, c7))); }

// Fused kernel: 512 threads = 8 waves; each wave owns 128 codes (2/lane:
// cbase+lane, cbase+64+lane; w in regs). 128-row z tile in LDS. 4 rows/iter,
// 8 indep FMA chains, 4 interleaved shfl-min chains, class-ordered ballots.
// Fused epilogue + per-block loss partial. 2 blocks/CU -> 4 waves/SIMD.
__global__ __launch_bounds__(512, 4)
void vq_fused_kernel(const float* __restrict__ z,
                     const float* __restrict__ cb,
                     float* __restrict__ out,
                     float* __restrict__ codes,
                     double* __restrict__ partials) {
    const int tid  = threadIdx.x;                     // 0..511
    const int wid  = tid >> 6;                        // 0..7
    const int lane = tid & 63;
    const int row0 = blockIdx.x * TROWS;              // tile base (same b)
    const int b    = row0 >> 13;                      // 8192 % 128 == 0
    const int t0   = row0 & (T_DIM - 1);

    __shared__ float4 zl[16][TROWS];                  // 32 KiB [kchunk][row]
    __shared__ float  zsql[TROWS];                    // 0.5 KiB
    __shared__ float2 res[8][TROWS];                  // 8 KiB  [wave][row]
    __shared__ int    codesl[TROWS];                  // 0.5 KiB

    // --- stage z tile cooperatively: thread (q=tid>>7, row=tid&127) loads
    //     16 scalars d = q*16..q*16+15 (coalesced along t within a wave) ---
    {
        const int q   = tid >> 7;                     // 0..3
        const int row = tid & (TROWS - 1);
        const float* zp = z + (size_t)b * (D_DIM * T_DIM)
                        + (size_t)(q * 16) * T_DIM + (t0 + row);
#pragma unroll
        for (int j = 0; j < 4; ++j) {
            float4 v;
            v.x = zp[(size_t)(j * 4 + 0) * T_DIM];
            v.y = zp[(size_t)(j * 4 + 1) * T_DIM];
            v.z = zp[(size_t)(j * 4 + 2) * T_DIM];
            v.w = zp[(size_t)(j * 4 + 3) * T_DIM];
            zl[q * 4 + j][row] = v;
        }
    }
    __syncthreads();

    // --- zsq from LDS bits (tid<128), exact PAIRWISE64 order ---
    if (tid < TROWS) {
        const float4 q0 = zl[0][tid],  q1 = zl[1][tid],  q2 = zl[2][tid],  q3 = zl[3][tid];
        const float4 q4 = zl[4][tid],  q5 = zl[5][tid],  q6 = zl[6][tid],  q7 = zl[7][tid];
        const float4 q8 = zl[8][tid],  q9 = zl[9][tid],  q10 = zl[10][tid], q11 = zl[11][tid];
        const float4 q12 = zl[12][tid], q13 = zl[13][tid], q14 = zl[14][tid], q15 = zl[15][tid];
        const float z0=q0.x,  z1=q0.y,  z2=q0.z,  z3=q0.w;
        const float z4=q1.x,  z5=q1.y,  z6=q1.z,  z7=q1.w;
        const float z8=q2.x,  z9=q2.y,  z10=q2.z, z11=q2.w;
        const float z12=q3.x, z13=q3.y, z14=q3.z, z15=q3.w;
        const float z16=q4.x, z17=q4.y, z18=q4.z, z19=q4.w;
        const float z20=q5.x, z21=q5.y, z22=q5.z, z23=q5.w;
        const float z24=q6.x, z25=q6.y, z26=q6.z, z27=q6.w;
        const float z28=q7.x, z29=q7.y, z30=q7.z, z31=q7.w;
        const float z32=q8.x, z33=q8.y, z34=q8.z, z35=q8.w;
        const float z36=q9.x, z37=q9.y, z38=q9.z, z39=q9.w;
        const float z40=q10.x, z41=q10.y, z42=q10.z, z43=q10.w;
        const float z44=q11.x, z45=q11.y, z46=q11.z, z47=q11.w;
        const float z48=q12.x, z49=q12.y, z50=q12.z, z51=q12.w;
        const float z52=q13.x, z53=q13.y, z54=q13.z, z55=q13.w;
        const float z56=q14.x, z57=q14.y, z58=q14.z, z59=q14.w;
        const float z60=q15.x, z61=q15.y, z62=q15.z, z63=q15.w;
        PAIRWISE64(z, zsq)
        zsql[tid] = zsq;
    }

    // --- my two codes' w into registers (one-time; 32 x float4) ---
    const int cbase = wid * 128;                      // wave's code base
    float4 wa[16], wb[16];
    {
        const float4* wpa = (const float4*)(cb + ((size_t)(cbase + lane)      << 6));
        const float4* wpb = (const float4*)(cb + ((size_t)(cbase + lane + 64) << 6));
#pragma unroll
        for (int kk = 0; kk < 16; ++kk) { wa[kk] = wpa[kk]; wb[kk] = wpb[kk]; }
    }
    WSQ_OF(wa, wsqA)
    WSQ_OF(wb, wsqB)
    __syncthreads();

    // --- row loop: 4 rows/iter, 8 FMA chains, 4 interleaved shfl chains ---
#pragma unroll 1
    for (int r = 0; r < TROWS; r += 4) {
        float aA0 = 0.f, aA1 = 0.f, aA2 = 0.f, aA3 = 0.f;
        float aB0 = 0.f, aB1 = 0.f, aB2 = 0.f, aB3 = 0.f;
#pragma unroll
        for (int kk = 0; kk < 16; ++kk) {
            const float4 zc0 = zl[kk][r + 0];   // broadcast reads
            const float4 zc1 = zl[kk][r + 1];
            const float4 zc2 = zl[kk][r + 2];
            const float4 zc3 = zl[kk][r + 3];
            const float4 WA = wa[kk];
            const float4 WB = wb[kk];
            aA0 = fmaf(zc0.x, WA.x, aA0); aA0 = fmaf(zc0.y, WA.y, aA0);
            aA0 = fmaf(zc0.z, WA.z, aA0); aA0 = fmaf(zc0.w, WA.w, aA0);
            aB0 = fmaf(zc0.x, WB.x, aB0); aB0 = fmaf(zc0.y, WB.y, aB0);
            aB0 = fmaf(zc0.z, WB.z, aB0); aB0 = fmaf(zc0.w, WB.w, aB0);
            aA1 = fmaf(zc1.x, WA.x, aA1); aA1 = fmaf(zc1.y, WA.y, aA1);
            aA1 = fmaf(zc1.z, WA.z, aA1); aA1 = fmaf(zc1.w, WA.w, aA1);
            aB1 = fmaf(zc1.x, WB.x, aB1); aB1 = fmaf(zc1.y, WB.y, aB1);
            aB1 = fmaf(zc1.z, WB.z, aB1); aB1 = fmaf(zc1.w, WB.w, aB1);
            aA2 = fmaf(zc2.x, WA.x, aA2); aA2 = fmaf(zc2.y, WA.y, aA2);
            aA2 = fmaf(zc2.z, WA.z, aA2); aA2 = fmaf(zc2.w, WA.w, aA2);
            aB2 = fmaf(zc2.x, WB.x, aB2); aB2 = fmaf(zc2.y, WB.y, aB2);
            aB2 = fmaf(zc2.z, WB.z, aB2); aB2 = fmaf(zc2.w, WB.w, aB2);
            aA3 = fmaf(zc3.x, WA.x, aA3); aA3 = fmaf(zc3.y, WA.y, aA3);
            aA3 = fmaf(zc3.z, WA.z, aA3); aA3 = fmaf(zc3.w, WA.w, aA3);
            aB3 = fmaf(zc3.x, WB.x, aB3); aB3 = fmaf(zc3.y, WB.y, aB3);
            aB3 = fmaf(zc3.z, WB.z, aB3); aB3 = fmaf(zc3.w, WB.w, aB3);
        }
        const float zr0 = zsql[r + 0];
        const float zr1 = zsql[r + 1];
        const float zr2 = zsql[r + 2];
        const float zr3 = zsql[r + 3];
        // d = (zsq - 2*dot) + wsq, each op individually rounded
        const float dA0 = __fadd_rn(__fsub_rn(zr0, __fmul_rn(2.0f, aA0)), wsqA);
        const float dB0 = __fadd_rn(__fsub_rn(zr0, __fmul_rn(2.0f, aB0)), wsqB);
        const float dA1 = __fadd_rn(__fsub_rn(zr1, __fmul_rn(2.0f, aA1)), wsqA);
        const float dB1 = __fadd_rn(__fsub_rn(zr1, __fmul_rn(2.0f, aB1)), wsqB);
        const float dA2 = __fadd_rn(__fsub_rn(zr2, __fmul_rn(2.0f, aA2)), wsqA);
        const float dB2 = __fadd_rn(__fsub_rn(zr2, __fmul_rn(2.0f, aB2)), wsqB);
        const float dA3 = __fadd_rn(__fsub_rn(zr3, __fmul_rn(2.0f, aA3)), wsqA);
        const float dB3 = __fadd_rn(__fsub_rn(zr3, __fmul_rn(2.0f, aB3)), wsqB);
        // pair pre-min (A wins ties: lower code)
        const bool tB0 = (dB0 < dA0); const float d0 = tB0 ? dB0 : dA0;
        const bool tB1 = (dB1 < dA1); const float d1 = tB1 ? dB1 : dA1;
        const bool tB2 = (dB2 < dA2); const float d2 = tB2 ? dB2 : dA2;
        const bool tB3 = (dB3 < dA3); const float d3 = tB3 ? dB3 : dA3;
        // 4 independent wave-min chains, interleaved -> pipelined bpermutes
        float m0 = d0, m1 = d1, m2 = d2, m3 = d3;
#pragma unroll
        for (int off = 32; off > 0; off >>= 1) {
            m0 = fminf(m0, __shfl_xor(m0, off, 64));
            m1 = fminf(m1, __shfl_xor(m1, off, 64));
            m2 = fminf(m2, __shfl_xor(m2, off, 64));
            m3 = fminf(m3, __shfl_xor(m3, off, 64));
        }
#define ARGMIN_J(mj, dj, tBj, outIdx) { \
        const unsigned long long mskA = __ballot((!tBj) && (dj == mj)); \
        const unsigned long long mskB = __ballot(tBj && (dj == mj)); \
        int code; \
        if (mskA) code = cbase + (__ffsll((long long)mskA) - 1); \
        else      code = cbase + 64 + (__ffsll((long long)mskB) - 1); \
        if (lane == 0) res[wid][outIdx] = make_float2(mj, (float)code); }
        ARGMIN_J(m0, d0, tB0, r + 0)
        ARGMIN_J(m1, d1, tB1, r + 1)
        ARGMIN_J(m2, d2, tB2, r + 2)
        ARGMIN_J(m3, d3, tB3, r + 3)
#undef ARGMIN_J
    }
    __syncthreads();

    // --- combine 8 waves (ascending wid == ascending code blocks) ---
    if (tid < TROWS) {
        float2 best = res[0][tid];
#pragma unroll
        for (int w = 1; w < 8; ++w) {
            const float2 p = res[w][tid];
            if (p.x < best.x) best = p;   // strict < keeps lower codes
        }
        codes[row0 + tid] = best.y;
        codesl[tid] = (int)best.y;
    }
    __syncthreads();

    // --- fused epilogue: thread (q,row) owns 16 d-values of one row ---
    // zl b128 reads (consecutive rows -> conflict-free); coalesced stores.
    const int q   = tid >> 7;                         // 0..3
    const int row = tid & (TROWS - 1);
    const int code = codesl[row];
    double lsum = 0.0;
    float* outb = out + (size_t)b * (D_DIM * T_DIM) + t0 + row;
#pragma unroll
    for (int j = 0; j < 4; ++j) {
        const int it = q * 4 + j;
        const float4 z4 = zl[it][row];
        const float4 w4 = *(const float4*)(cb + ((size_t)code << 6) + (it << 2));
        const float df0 = __fsub_rn(w4.x, z4.x);
        const float df1 = __fsub_rn(w4.y, z4.y);
        const float df2 = __fsub_rn(w4.z, z4.z);
        const float df3 = __fsub_rn(w4.w, z4.w);
        outb[(size_t)((it << 2) + 0) * T_DIM] = __fadd_rn(z4.x, df0);
        outb[(size_t)((it << 2) + 1) * T_DIM] = __fadd_rn(z4.y, df1);
        outb[(size_t)((it << 2) + 2) * T_DIM] = __fadd_rn(z4.z, df2);
        outb[(size_t)((it << 2) + 3) * T_DIM] = __fadd_rn(z4.w, df3);
        lsum += (double)df0 * df0 + (double)df1 * df1
              + (double)df2 * df2 + (double)df3 * df3;
    }
    // wave reduce (double) then block reduce via LDS
#pragma unroll
    for (int o2 = 32; o2 > 0; o2 >>= 1) lsum += __shfl_down(lsum, o2, 64);
    __shared__ double redd[8];
    if (lane == 0) redd[wid] = lsum;
    __syncthreads();
    if (tid == 0) {
        partials[blockIdx.x] = ((redd[0] + redd[1]) + (redd[2] + redd[3]))
                             + ((redd[4] + redd[5]) + (redd[6] + redd[7]));
    }
}

__global__ void vq_loss_kernel(const double* __restrict__ partials,
                               float* __restrict__ out_loss) {
    double s = 0.0;
    for (int i = threadIdx.x; i < NBLKS; i += 256) s += partials[i];
#pragma unroll
    for (int o = 32; o > 0; o >>= 1) s += __shfl_down(s, o, 64);
    __shared__ double red[4];
    if ((threadIdx.x & 63) == 0) red[threadIdx.x >> 6] = s;
    __syncthreads();
    if (threadIdx.x == 0) {
        double tot = (red[0] + red[1]) + (red[2] + red[3]);
        // vq_loss = codebook_loss + 0.25*commitment_loss = 1.25*mean(diff^2)
        out_loss[0] = (float)(1.25 * tot / (double)NELEM);
    }
}

extern "C" void kernel_launch(void* const* d_in, const int* in_sizes, int n_in,
                              void* d_out, int out_size, void* d_ws, size_t ws_size,
                              hipStream_t stream) {
    const float* z  = (const float*)d_in[0];   // 4194304
    const float* cb = (const float*)d_in[1];   // 65536

    float* out      = (float*)d_out;
    float* out_loss = out + NELEM;             // index 4194304
    float* codes    = out + NELEM + 1;         // 65536 floats

    double* partials = (double*)d_ws;          // 4 KiB (512 doubles)

    vq_fused_kernel<<<NBLKS, 512, 0, stream>>>(z, cb, out, codes, partials);
    vq_loss_kernel<<<1, 256, 0, stream>>>(partials, out_loss);
}

// Round 13
// 219.930 us; speedup vs baseline: 1.5153x; 1.3762x over previous
//
#include <hip/hip_runtime.h>

// VectorQuantizer: z (8,64,8192) f32, codebook (1024,64) f32
// Outputs (concatenated f32): z_q_st [4194304], vq_loss [1], codes [65536]
//
// codes must match numpy fp32 argmin BIT-EXACTLY -> replicate numpy op order:
//   zsq/wsq: pairwise_sum n=64 (8 serial column accumulators, rounded squares)
//   dot:     single serial FMA chain over k ascending (BLAS sgemm order)
//   dist:    fl(fl(zsq - fl(2*dot)) + wsq), argmin = first occurrence of min.
//
// Evidence ledger:
//   R6-R9 190us (w s_load drains) | R11 500us (VMEM 64x amp) | R12 209 |
//   R13 175 | R14 1667 SPILL | R15 fused 8w x 2codes/lane 256-row tile:
//   184.7us kernel / 223.8 total, VALUBusy 55%, 2 waves/SIMD | R16 (1 w/SIMD)
//   288us latency-exposed | R17 launch_bounds(512,4): VGPR=64, FETCH 494MB --
//   128-reg cap SPILLED the 128-float w array. CONCLUSION: w-in-regs and
//   >=4 waves/SIMD are mutually exclusive (512-reg file). TLP capped at 2.
//   Refined model: b128 broadcast DELIVERS 1KB/instr (256B/cy return) ->
//   LDS floor ~55us ~= VALU floor 55us; pipes overlap; ideal ~80us. R15's
//   184.7 = latency un-hiding at 2 waves/SIMD. Remaining lever: ILP.
// R19 (this round): R15 verbatim + 8 ROWS/ITER (16 indep b128 in flight
//   per kk-step; 8 interleaved shfl chains halve reduction episodes) +
//   R17's conflict-free b128 epilogue. Regs ~200 < 256 at (512,2).
//   Chain order per (row,code) untouched -> bit-exact.
//   Predict: kernel 184.7 -> 135-160us; total -> 170-195; VALUBusy 65-75%;
//   VGPR ~170-210; FETCH ~9.3MB.
//   Falsifier A: FETCH GB-scale = spill -> 6 rows/iter.
//   Falsifier B: flat dur -> ILP exhausted -> SMEM-z + DPP-reduce redesign.

#define T_DIM 8192
#define D_DIM 64
#define C_DIM 1024
#define B_DIM 8
#define NROWS (B_DIM * T_DIM)           // 65536 vectors
#define NELEM (B_DIM * D_DIM * T_DIM)   // 4194304 elements
#define NBLKS (NROWS / 256)             // 256 fused blocks

#define R64(M) M(0) M(1) M(2) M(3) M(4) M(5) M(6) M(7) \
  M(8) M(9) M(10) M(11) M(12) M(13) M(14) M(15) \
  M(16) M(17) M(18) M(19) M(20) M(21) M(22) M(23) \
  M(24) M(25) M(26) M(27) M(28) M(29) M(30) M(31) \
  M(32) M(33) M(34) M(35) M(36) M(37) M(38) M(39) \
  M(40) M(41) M(42) M(43) M(44) M(45) M(46) M(47) \
  M(48) M(49) M(50) M(51) M(52) M(53) M(54) M(55) \
  M(56) M(57) M(58) M(59) M(60) M(61) M(62) M(63)

#define SQ_(x) __fmul_rn(x, x)
#define AD_(a, b) __fadd_rn(a, b)

// numpy pairwise_sum of 64 pre-rounded squares of scalars p0..p63 -> dst.
#define PAIRWISE64(p, dst) \
  float pr0 = SQ_(p##0);  pr0 = AD_(pr0, SQ_(p##8));  pr0 = AD_(pr0, SQ_(p##16)); pr0 = AD_(pr0, SQ_(p##24)); pr0 = AD_(pr0, SQ_(p##32)); pr0 = AD_(pr0, SQ_(p##40)); pr0 = AD_(pr0, SQ_(p##48)); pr0 = AD_(pr0, SQ_(p##56)); \
  float pr1 = SQ_(p##1);  pr1 = AD_(pr1, SQ_(p##9));  pr1 = AD_(pr1, SQ_(p##17)); pr1 = AD_(pr1, SQ_(p##25)); pr1 = AD_(pr1, SQ_(p##33)); pr1 = AD_(pr1, SQ_(p##41)); pr1 = AD_(pr1, SQ_(p##49)); pr1 = AD_(pr1, SQ_(p##57)); \
  float pr2 = SQ_(p##2);  pr2 = AD_(pr2, SQ_(p##10)); pr2 = AD_(pr2, SQ_(p##18)); pr2 = AD_(pr2, SQ_(p##26)); pr2 = AD_(pr2, SQ_(p##34)); pr2 = AD_(pr2, SQ_(p##42)); pr2 = AD_(pr2, SQ_(p##50)); pr2 = AD_(pr2, SQ_(p##58)); \
  float pr3 = SQ_(p##3);  pr3 = AD_(pr3, SQ_(p##11)); pr3 = AD_(pr3, SQ_(p##19)); pr3 = AD_(pr3, SQ_(p##27)); pr3 = AD_(pr3, SQ_(p##35)); pr3 = AD_(pr3, SQ_(p##43)); pr3 = AD_(pr3, SQ_(p##51)); pr3 = AD_(pr3, SQ_(p##59)); \
  float pr4 = SQ_(p##4);  pr4 = AD_(pr4, SQ_(p##12)); pr4 = AD_(pr4, SQ_(p##20)); pr4 = AD_(pr4, SQ_(p##28)); pr4 = AD_(pr4, SQ_(p##36)); pr4 = AD_(pr4, SQ_(p##44)); pr4 = AD_(pr4, SQ_(p##52)); pr4 = AD_(pr4, SQ_(p##60)); \
  float pr5 = SQ_(p##5);  pr5 = AD_(pr5, SQ_(p##13)); pr5 = AD_(pr5, SQ_(p##21)); pr5 = AD_(pr5, SQ_(p##29)); pr5 = AD_(pr5, SQ_(p##37)); pr5 = AD_(pr5, SQ_(p##45)); pr5 = AD_(pr5, SQ_(p##53)); pr5 = AD_(pr5, SQ_(p##61)); \
  float pr6 = SQ_(p##6);  pr6 = AD_(pr6, SQ_(p##14)); pr6 = AD_(pr6, SQ_(p##22)); pr6 = AD_(pr6, SQ_(p##30)); pr6 = AD_(pr6, SQ_(p##38)); pr6 = AD_(pr6, SQ_(p##46)); pr6 = AD_(pr6, SQ_(p##54)); pr6 = AD_(pr6, SQ_(p##62)); \
  float pr7 = SQ_(p##7);  pr7 = AD_(pr7, SQ_(p##15)); pr7 = AD_(pr7, SQ_(p##23)); pr7 = AD_(pr7, SQ_(p##31)); pr7 = AD_(pr7, SQ_(p##39)); pr7 = AD_(pr7, SQ_(p##47)); pr7 = AD_(pr7, SQ_(p##55)); pr7 = AD_(pr7, SQ_(p##63)); \
  float dst = AD_(AD_(AD_(pr0, pr1), AD_(pr2, pr3)), AD_(AD_(pr4, pr5), AD_(pr6, pr7)));

// Same pairwise order, sourced from a float4[16] register array.
#define WSQ_OF(arr, dst) float dst; { \
  float c0 = SQ_(arr[0].x); c0=AD_(c0,SQ_(arr[2].x)); c0=AD_(c0,SQ_(arr[4].x)); c0=AD_(c0,SQ_(arr[6].x)); c0=AD_(c0,SQ_(arr[8].x)); c0=AD_(c0,SQ_(arr[10].x)); c0=AD_(c0,SQ_(arr[12].x)); c0=AD_(c0,SQ_(arr[14].x)); \
  float c1 = SQ_(arr[0].y); c1=AD_(c1,SQ_(arr[2].y)); c1=AD_(c1,SQ_(arr[4].y)); c1=AD_(c1,SQ_(arr[6].y)); c1=AD_(c1,SQ_(arr[8].y)); c1=AD_(c1,SQ_(arr[10].y)); c1=AD_(c1,SQ_(arr[12].y)); c1=AD_(c1,SQ_(arr[14].y)); \
  float c2 = SQ_(arr[0].z); c2=AD_(c2,SQ_(arr[2].z)); c2=AD_(c2,SQ_(arr[4].z)); c2=AD_(c2,SQ_(arr[6].z)); c2=AD_(c2,SQ_(arr[8].z)); c2=AD_(c2,SQ_(arr[10].z)); c2=AD_(c2,SQ_(arr[12].z)); c2=AD_(c2,SQ_(arr[14].z)); \
  float c3 = SQ_(arr[0].w); c3=AD_(c3,SQ_(arr[2].w)); c3=AD_(c3,SQ_(arr[4].w)); c3=AD_(c3,SQ_(arr[6].w)); c3=AD_(c3,SQ_(arr[8].w)); c3=AD_(c3,SQ_(arr[10].w)); c3=AD_(c3,SQ_(arr[12].w)); c3=AD_(c3,SQ_(arr[14].w)); \
  float c4 = SQ_(arr[1].x); c4=AD_(c4,SQ_(arr[3].x)); c4=AD_(c4,SQ_(arr[5].x)); c4=AD_(c4,SQ_(arr[7].x)); c4=AD_(c4,SQ_(arr[9].x)); c4=AD_(c4,SQ_(arr[11].x)); c4=AD_(c4,SQ_(arr[13].x)); c4=AD_(c4,SQ_(arr[15].x)); \
  float c5 = SQ_(arr[1].y); c5=AD_(c5,SQ_(arr[3].y)); c5=AD_(c5,SQ_(arr[5].y)); c5=AD_(c5,SQ_(arr[7].y)); c5=AD_(c5,SQ_(arr[9].y)); c5=AD_(c5,SQ_(arr[11].y)); c5=AD_(c5,SQ_(arr[13].y)); c5=AD_(c5,SQ_(arr[15].y)); \
  float c6 = SQ_(arr[1].z); c6=AD_(c6,SQ_(arr[3].z)); c6=AD_(c6,SQ_(arr[5].z)); c6=AD_(c6,SQ_(arr[7].z)); c6=AD_(c6,SQ_(arr[9].z)); c6=AD_(c6,SQ_(arr[11].z)); c6=AD_(c6,SQ_(arr[13].z)); c6=AD_(c6,SQ_(arr[15].z)); \
  float c7 = SQ_(arr[1].w); c7=AD_(c7,SQ_(arr[3].w)); c7=AD_(c7,SQ_(arr[5].w)); c7=AD_(c7,SQ_(arr[7].w)); c7=AD_(c7,SQ_(arr[9].w)); c7=AD_(c7,SQ_(arr[11].w)); c7=AD_(c7,SQ_(arr[13].w)); c7=AD_(c7,SQ_(arr[15].w)); \
  dst = AD_(AD_(AD_(c0, c1), AD_(c2, c3)), AD_(AD_(c4, c5), AD_(c6, c7))); }

// One FMA chain-step: 4 serial FMAs (k ascending within the float4).
#define FM4(acc, zc, W) \
    acc = fmaf(zc.x, W.x, acc); acc = fmaf(zc.y, W.y, acc); \
    acc = fmaf(zc.z, W.z, acc); acc = fmaf(zc.w, W.w, acc);

// Fused kernel: 512 threads = 8 waves; each wave owns 128 codes (2/lane:
// cbase+lane, cbase+64+lane; w in regs). 256-row z tile in LDS (broadcast
// reads). 8 ROWS/ITER: 16 indep FMA chains, 16 b128 in flight per kk-step,
// 8 interleaved shfl-min chains. Fused epilogue + loss partial.
__global__ __launch_bounds__(512, 2)
void vq_fused_kernel(const float* __restrict__ z,
                     const float* __restrict__ cb,
                     float* __restrict__ out,
                     float* __restrict__ codes,
                     double* __restrict__ partials) {
    const int tid  = threadIdx.x;                     // 0..511
    const int wid  = tid >> 6;                        // 0..7
    const int lane = tid & 63;
    const int row0 = blockIdx.x * 256;                // tile base (same b)
    const int b    = row0 >> 13;                      // 8192 % 256 == 0
    const int t0   = row0 & (T_DIM - 1);

    __shared__ float4 zl[16][256];                    // 64 KiB  [kchunk][row]
    __shared__ float  zsql[256];                      // 1 KiB
    __shared__ float2 res[8][256];                    // 16 KiB  [wave][row]
    __shared__ int    codesl[256];                    // 1 KiB

    // --- stage z tile: threads 0..255 handle row row0+tid (coalesced) ---
    if (tid < 256) {
        const float* zp = z + (size_t)b * (D_DIM * T_DIM) + (t0 + tid);
#define LOADZ(k) float z##k = zp[(size_t)k * T_DIM];
        R64(LOADZ)
#undef LOADZ
        PAIRWISE64(z, zsq)
        zsql[tid] = zsq;
        zl[ 0][tid] = make_float4(z0,  z1,  z2,  z3);
        zl[ 1][tid] = make_float4(z4,  z5,  z6,  z7);
        zl[ 2][tid] = make_float4(z8,  z9,  z10, z11);
        zl[ 3][tid] = make_float4(z12, z13, z14, z15);
        zl[ 4][tid] = make_float4(z16, z17, z18, z19);
        zl[ 5][tid] = make_float4(z20, z21, z22, z23);
        zl[ 6][tid] = make_float4(z24, z25, z26, z27);
        zl[ 7][tid] = make_float4(z28, z29, z30, z31);
        zl[ 8][tid] = make_float4(z32, z33, z34, z35);
        zl[ 9][tid] = make_float4(z36, z37, z38, z39);
        zl[10][tid] = make_float4(z40, z41, z42, z43);
        zl[11][tid] = make_float4(z44, z45, z46, z47);
        zl[12][tid] = make_float4(z48, z49, z50, z51);
        zl[13][tid] = make_float4(z52, z53, z54, z55);
        zl[14][tid] = make_float4(z56, z57, z58, z59);
        zl[15][tid] = make_float4(z60, z61, z62, z63);
    }

    // --- my two codes' w into registers (one-time; 32 x float4) ---
    const int cbase = wid * 128;                      // wave's code base
    float4 wa[16], wb[16];
    {
        const float4* wpa = (const float4*)(cb + ((size_t)(cbase + lane)      << 6));
        const float4* wpb = (const float4*)(cb + ((size_t)(cbase + lane + 64) << 6));
#pragma unroll
        for (int kk = 0; kk < 16; ++kk) { wa[kk] = wpa[kk]; wb[kk] = wpb[kk]; }
    }
    WSQ_OF(wa, wsqA)
    WSQ_OF(wb, wsqB)
    __syncthreads();

    // --- row loop: 8 rows/iter, 16 indep FMA chains, 8 shfl chains ---
#pragma unroll 1
    for (int r = 0; r < 256; r += 8) {
        float aA0 = 0.f, aA1 = 0.f, aA2 = 0.f, aA3 = 0.f;
        float aA4 = 0.f, aA5 = 0.f, aA6 = 0.f, aA7 = 0.f;
        float aB0 = 0.f, aB1 = 0.f, aB2 = 0.f, aB3 = 0.f;
        float aB4 = 0.f, aB5 = 0.f, aB6 = 0.f, aB7 = 0.f;
#pragma unroll
        for (int kk = 0; kk < 16; ++kk) {
            const float4 zc0 = zl[kk][r + 0];   // broadcast reads
            const float4 zc1 = zl[kk][r + 1];
            const float4 zc2 = zl[kk][r + 2];
            const float4 zc3 = zl[kk][r + 3];
            const float4 zc4 = zl[kk][r + 4];
            const float4 zc5 = zl[kk][r + 5];
            const float4 zc6 = zl[kk][r + 6];
            const float4 zc7 = zl[kk][r + 7];
            const float4 WA = wa[kk];
            const float4 WB = wb[kk];
            FM4(aA0, zc0, WA) FM4(aA1, zc1, WA) FM4(aA2, zc2, WA) FM4(aA3, zc3, WA)
            FM4(aA4, zc4, WA) FM4(aA5, zc5, WA) FM4(aA6, zc6, WA) FM4(aA7, zc7, WA)
            FM4(aB0, zc0, WB) FM4(aB1, zc1, WB) FM4(aB2, zc2, WB) FM4(aB3, zc3, WB)
            FM4(aB4, zc4, WB) FM4(aB5, zc5, WB) FM4(aB6, zc6, WB) FM4(aB7, zc7, WB)
        }
        // d = (zsq - 2*dot) + wsq, each op individually rounded
#define DISTP(j) \
        const float zr##j = zsql[r + j]; \
        const float dA##j = __fadd_rn(__fsub_rn(zr##j, __fmul_rn(2.0f, aA##j)), wsqA); \
        const float dB##j = __fadd_rn(__fsub_rn(zr##j, __fmul_rn(2.0f, aB##j)), wsqB); \
        const bool tB##j = (dB##j < dA##j); \
        const float d##j = tB##j ? dB##j : dA##j;
        DISTP(0) DISTP(1) DISTP(2) DISTP(3)
        DISTP(4) DISTP(5) DISTP(6) DISTP(7)
#undef DISTP
        // 8 independent wave-min chains, interleaved -> pipelined bpermutes
        float m0 = d0, m1 = d1, m2 = d2, m3 = d3;
        float m4 = d4, m5 = d5, m6 = d6, m7 = d7;
#pragma unroll
        for (int off = 32; off > 0; off >>= 1) {
            m0 = fminf(m0, __shfl_xor(m0, off, 64));
            m1 = fminf(m1, __shfl_xor(m1, off, 64));
            m2 = fminf(m2, __shfl_xor(m2, off, 64));
            m3 = fminf(m3, __shfl_xor(m3, off, 64));
            m4 = fminf(m4, __shfl_xor(m4, off, 64));
            m5 = fminf(m5, __shfl_xor(m5, off, 64));
            m6 = fminf(m6, __shfl_xor(m6, off, 64));
            m7 = fminf(m7, __shfl_xor(m7, off, 64));
        }
        // first-min index per row: A-class codes < B-class; lane order ==
        // code order within a class -> lowest set lane wins.
#define ARGMIN_J(j) { \
        const unsigned long long mskA = __ballot((!tB##j) && (d##j == m##j)); \
        const unsigned long long mskB = __ballot(tB##j && (d##j == m##j)); \
        int code; \
        if (mskA) code = cbase + (__ffsll((long long)mskA) - 1); \
        else      code = cbase + 64 + (__ffsll((long long)mskB) - 1); \
        if (lane == 0) res[wid][r + j] = make_float2(m##j, (float)code); }
        ARGMIN_J(0) ARGMIN_J(1) ARGMIN_J(2) ARGMIN_J(3)
        ARGMIN_J(4) ARGMIN_J(5) ARGMIN_J(6) ARGMIN_J(7)
#undef ARGMIN_J
    }
    __syncthreads();

    // --- combine 8 waves (ascending wid == ascending code blocks) ---
    if (tid < 256) {
        float2 best = res[0][tid];
#pragma unroll
        for (int w = 1; w < 8; ++w) {
            const float2 p = res[w][tid];
            if (p.x < best.x) best = p;   // strict < keeps lower codes
        }
        codes[row0 + tid] = best.y;
        codesl[tid] = (int)best.y;
    }
    __syncthreads();

    // --- fused epilogue: thread (q=tid>>8, row=tid&255) owns 8 float4
    //     chunks of one row. zl b128 reads at 16B lane stride = conflict-
    //     free; coalesced stores per d-plane. out = fl(z + fl(w - z)). ---
    const int q   = tid >> 8;                         // 0..1
    const int row = tid & 255;
    const int code = codesl[row];
    double lsum = 0.0;
    float* outb = out + (size_t)b * (D_DIM * T_DIM) + t0 + row;
#pragma unroll
    for (int j = 0; j < 8; ++j) {
        const int it = q * 8 + j;
        const float4 z4 = zl[it][row];
        const float4 w4 = *(const float4*)(cb + ((size_t)code << 6) + (it << 2));
        const float df0 = __fsub_rn(w4.x, z4.x);
        const float df1 = __fsub_rn(w4.y, z4.y);
        const float df2 = __fsub_rn(w4.z, z4.z);
        const float df3 = __fsub_rn(w4.w, z4.w);
        outb[(size_t)((it << 2) + 0) * T_DIM] = __fadd_rn(z4.x, df0);
        outb[(size_t)((it << 2) + 1) * T_DIM] = __fadd_rn(z4.y, df1);
        outb[(size_t)((it << 2) + 2) * T_DIM] = __fadd_rn(z4.z, df2);
        outb[(size_t)((it << 2) + 3) * T_DIM] = __fadd_rn(z4.w, df3);
        lsum += (double)df0 * df0 + (double)df1 * df1
              + (double)df2 * df2 + (double)df3 * df3;
    }
    // wave reduce (double) then block reduce via LDS
#pragma unroll
    for (int o2 = 32; o2 > 0; o2 >>= 1) lsum += __shfl_down(lsum, o2, 64);
    __shared__ double redd[8];
    if (lane == 0) redd[wid] = lsum;
    __syncthreads();
    if (tid == 0) {
        partials[blockIdx.x] = ((redd[0] + redd[1]) + (redd[2] + redd[3]))
                             + ((redd[4] + redd[5]) + (redd[6] + redd[7]));
    }
}

__global__ void vq_loss_kernel(const double* __restrict__ partials,
                               float* __restrict__ out_loss) {
    double s = 0.0;
    for (int i = threadIdx.x; i < NBLKS; i += 256) s += partials[i];
#pragma unroll
    for (int o = 32; o > 0; o >>= 1) s += __shfl_down(s, o, 64);
    __shared__ double red[4];
    if ((threadIdx.x & 63) == 0) red[threadIdx.x >> 6] = s;
    __syncthreads();
    if (threadIdx.x == 0) {
        double tot = (red[0] + red[1]) + (red[2] + red[3]);
        // vq_loss = codebook_loss + 0.25*commitment_loss = 1.25*mean(diff^2)
        out_loss[0] = (float)(1.25 * tot / (double)NELEM);
    }
}

extern "C" void kernel_launch(void* const* d_in, const int* in_sizes, int n_in,
                              void* d_out, int out_size, void* d_ws, size_t ws_size,
                              hipStream_t stream) {
    const float* z  = (const float*)d_in[0];   // 4194304
    const float* cb = (const float*)d_in[1];   // 65536

    float* out      = (float*)d_out;
    float* out_loss = out + NELEM;             // index 4194304
    float* codes    = out + NELEM + 1;         // 65536 floats

    double* partials = (double*)d_ws;          // 2 KiB (256 doubles)

    vq_fused_kernel<<<NBLKS, 512, 0, stream>>>(z, cb, out, codes, partials);
    vq_loss_kernel<<<1, 256, 0, stream>>>(partials, out_loss);
}